// Round 1
// baseline (167.225 us; speedup 1.0000x reference)
//
#include <hip/hip_runtime.h>
#include <hip/hip_bf16.h>

// Problem constants (match reference)
constexpr int BB = 16384;   // batch
constexpr int CC = 2048;    // classes
constexpr int DD = 256;     // dim
constexpr float THR   = 0.8f;
constexpr float M_NEG = 0.3f;
constexpr float EPSN  = 1e-8f;

typedef __bf16 bf16x8 __attribute__((ext_vector_type(8)));
typedef float  f32x4  __attribute__((ext_vector_type(4)));

// ---------------- workspace layout (bytes) ----------------
// [0)            csum   : C*D*4 = 2,097,152   (zeroed each launch)
// [2,097,152)    cnt    : C*4   = 8,192       (zeroed)
// [2,105,344)    Ecnt   : 4 (pad->64)         (zeroed)
// [2,105,408)    cls    : B*4   = 65,536
// [2,170,944)    exists : C*4   = 8,192
// [2,179,136)    pn     : B*D*2 = 8,388,608   (bf16)
// [10,567,744)   cn     : C*D*2 = 1,048,576   (bf16)
// total 11,616,320 bytes

// Kernel 1: per-row class find + centroid sum + histogram.
// One block (256 thr) per row; reads labels row (8KB) coalesced.
__global__ __launch_bounds__(256) void k_cls_centroid(
    const float* __restrict__ labels, const float* __restrict__ preds,
    float* __restrict__ csum, int* __restrict__ cnt, int* __restrict__ cls) {
  int b = blockIdx.x;
  int t = threadIdx.x;
  __shared__ int s_idx;
  if (t == 0) s_idx = -1;
  __syncthreads();
  const float4* lrow = reinterpret_cast<const float4*>(labels + (size_t)b * CC);
#pragma unroll
  for (int i = 0; i < 2; ++i) {
    float4 v = lrow[t * 2 + i];
    int base = (t * 2 + i) * 4;
    if (v.x >= THR) s_idx = base + 0;
    if (v.y >= THR) s_idx = base + 1;
    if (v.z >= THR) s_idx = base + 2;
    if (v.w >= THR) s_idx = base + 3;
  }
  __syncthreads();
  int cl = s_idx;
  if (t == 0) {
    cls[b] = cl;
    if (cl >= 0) atomicAdd(&cnt[cl], 1);
  }
  if (cl >= 0) {
    // thread t owns dim element t (D == blockDim)
    atomicAdd(&csum[cl * DD + t], preds[(size_t)b * DD + t]);
  }
}

// Kernel 2: pn = preds / max(||row||, EPS), stored bf16. One block per row.
__global__ __launch_bounds__(256) void k_pn(const float* __restrict__ preds,
                                            unsigned short* __restrict__ pn) {
  int b = blockIdx.x;
  int t = threadIdx.x;
  float v = preds[(size_t)b * DD + t];
  float s = v * v;
#pragma unroll
  for (int o = 32; o > 0; o >>= 1) s += __shfl_xor(s, o);
  __shared__ float red[4];
  int wave = t >> 6, lane = t & 63;
  if (lane == 0) red[wave] = s;
  __syncthreads();
  float tot = red[0] + red[1] + red[2] + red[3];
  float inv = 1.0f / fmaxf(sqrtf(tot), EPSN);
  __bf16 h = (__bf16)(v * inv);
  pn[(size_t)b * DD + t] = *reinterpret_cast<unsigned short*>(&h);
}

// Kernel 3: finalize centroids -> normalized cn (bf16), exists flags, E count.
__global__ __launch_bounds__(256) void k_cn(
    const float* __restrict__ csum, const int* __restrict__ cnt,
    unsigned short* __restrict__ cn, int* __restrict__ exists,
    int* __restrict__ Ecnt) {
  int c = blockIdx.x;
  int t = threadIdx.x;
  int n = cnt[c];
  float mean = csum[c * DD + t] / (float)(n > 0 ? n : 1);
  float s = mean * mean;
#pragma unroll
  for (int o = 32; o > 0; o >>= 1) s += __shfl_xor(s, o);
  __shared__ float red[4];
  int wave = t >> 6, lane = t & 63;
  if (lane == 0) red[wave] = s;
  __syncthreads();
  float tot = red[0] + red[1] + red[2] + red[3];
  float inv = 1.0f / fmaxf(sqrtf(tot), EPSN);
  __bf16 h = (__bf16)(mean * inv);
  cn[c * DD + t] = *reinterpret_cast<unsigned short*>(&h);
  if (t == 0) {
    exists[c] = (n > 0) ? 1 : 0;
    if (n > 0) atomicAdd(Ecnt, 1);
  }
}

// Kernel 4: fused cos_all GEMM (pn @ cn^T) + diagonal pos + hinge neg,
// reduced to a single scalar via per-block reduce + atomicAdd.
// Block tile 128x128, 4 waves; wave = 32 rows x 128 cols = 2x8 MFMA tiles.
// mfma_f32_16x16x32_bf16 layouts:
//   A: lane holds row (lane&15), k = (lane>>4)*8 + e   (8 consecutive bf16)
//   B: lane holds col (lane&15), k = (lane>>4)*8 + e
//   D: col = lane&15, row = (lane>>4)*4 + reg          (m89-verified)
__global__ __launch_bounds__(256) void k_loss(
    const unsigned short* __restrict__ pn, const unsigned short* __restrict__ cn,
    const int* __restrict__ cls, const int* __restrict__ exists,
    const int* __restrict__ Ecnt, float* __restrict__ out) {
  constexpr int BM = 128, BN = 128;
  int bid = blockIdx.x;
  int mtile = bid % (BB / BM);
  int ntile = bid / (BB / BM);
  int rowbase = mtile * BM, colbase = ntile * BN;
  int tid = threadIdx.x, w = tid >> 6, lane = tid & 63;
  int r16 = lane & 15, khi = lane >> 4;  // khi in 0..3
  int wrow = rowbase + w * 32;

  f32x4 acc[2][8];
#pragma unroll
  for (int i = 0; i < 2; ++i)
#pragma unroll
    for (int j = 0; j < 8; ++j) acc[i][j] = {0.f, 0.f, 0.f, 0.f};

  const unsigned short* pA0 = pn + (size_t)(wrow + r16) * DD + khi * 8;
  const unsigned short* pA1 = pA0 + 16 * DD;
  const unsigned short* pB  = cn + (size_t)(colbase + r16) * DD + khi * 8;

#pragma unroll
  for (int kk = 0; kk < 8; ++kk) {
    int ko = kk * 32;
    bf16x8 a0 = *reinterpret_cast<const bf16x8*>(pA0 + ko);
    bf16x8 a1 = *reinterpret_cast<const bf16x8*>(pA1 + ko);
#pragma unroll
    for (int j = 0; j < 8; ++j) {
      bf16x8 bj = *reinterpret_cast<const bf16x8*>(pB + (size_t)j * 16 * DD + ko);
      acc[0][j] = __builtin_amdgcn_mfma_f32_16x16x32_bf16(a0, bj, acc[0][j], 0, 0, 0);
      acc[1][j] = __builtin_amdgcn_mfma_f32_16x16x32_bf16(a1, bj, acc[1][j], 0, 0, 0);
    }
  }

  // Epilogue: pos (diagonal) + hinge neg, all scaled into one scalar.
  int E = *Ecnt;
  float inv_B = 1.0f / (float)BB;
  float inv_neg = inv_B / (float)((E - 1) > 0 ? (E - 1) : 1);

  int clsr[2][4];
#pragma unroll
  for (int i = 0; i < 2; ++i)
#pragma unroll
    for (int r = 0; r < 4; ++r) clsr[i][r] = cls[wrow + i * 16 + khi * 4 + r];
  int exs[8];
#pragma unroll
  for (int j = 0; j < 8; ++j) exs[j] = exists[colbase + j * 16 + r16];

  float local = 0.f;
#pragma unroll
  for (int i = 0; i < 2; ++i)
#pragma unroll
    for (int j = 0; j < 8; ++j) {
      int ccol = colbase + j * 16 + r16;
#pragma unroll
      for (int r = 0; r < 4; ++r) {
        float v = acc[i][j][r];
        if (ccol == clsr[i][r])
          local += (1.0f - v) * inv_B;           // pos: 1 - cos(b, cls[b])
        else if (exs[j])
          local += fmaxf(v - 0.7f, 0.f) * inv_neg;  // relu(M_NEG-(1-cos))
      }
    }

  // block reduce -> one atomic per block
#pragma unroll
  for (int o = 32; o > 0; o >>= 1) local += __shfl_xor(local, o);
  __shared__ float red[4];
  if (lane == 0) red[w] = local;
  __syncthreads();
  if (tid == 0) atomicAdd(out, red[0] + red[1] + red[2] + red[3]);
}

extern "C" void kernel_launch(void* const* d_in, const int* in_sizes, int n_in,
                              void* d_out, int out_size, void* d_ws, size_t ws_size,
                              hipStream_t stream) {
  const float* preds  = (const float*)d_in[0];
  const float* labels = (const float*)d_in[1];
  float* out = (float*)d_out;

  char* ws = (char*)d_ws;
  float*          csum   = (float*)(ws + 0);
  int*            cnt    = (int*)(ws + 2097152);
  int*            Ecnt   = (int*)(ws + 2105344);
  int*            cls    = (int*)(ws + 2105408);
  int*            exists = (int*)(ws + 2170944);
  unsigned short* pn     = (unsigned short*)(ws + 2179136);
  unsigned short* cn     = (unsigned short*)(ws + 10567744);

  // zero accumulators (csum + cnt + Ecnt) and the output scalar
  hipMemsetAsync(ws, 0, 2105408, stream);
  hipMemsetAsync(d_out, 0, sizeof(float), stream);

  k_cls_centroid<<<BB, 256, 0, stream>>>(labels, preds, csum, cnt, cls);
  k_pn<<<BB, 256, 0, stream>>>(preds, pn);
  k_cn<<<CC, 256, 0, stream>>>(csum, cnt, cn, exists, Ecnt);
  k_loss<<<(BB / 128) * (CC / 128), 256, 0, stream>>>(pn, cn, cls, exists, Ecnt, out);
}

// Round 2
// 118.331 us; speedup vs baseline: 1.4132x; 1.4132x over previous
//
#include <hip/hip_runtime.h>
#include <hip/hip_bf16.h>

// Problem constants (match reference)
constexpr int BB = 16384;   // batch
constexpr int CC = 2048;    // classes
constexpr int DD = 256;     // dim
constexpr float THR   = 0.8f;
constexpr float EPSN  = 1e-8f;

typedef __bf16 bf16x8 __attribute__((ext_vector_type(8)));
typedef float  f32x4  __attribute__((ext_vector_type(4)));

// ---------------- workspace layout (bytes) ----------------
// [0)            csum   : C*D*4 = 2,097,152   (zeroed each launch)
// [2,097,152)    cnt    : C*4   = 8,192       (zeroed)
// [2,105,344)    Ecnt   : 4 (pad->64)         (zeroed)
// [2,105,408)    cls    : B*4   = 65,536
// [2,170,944)    exists : C*4   = 8,192
// [2,179,136)    pn     : B*D*2 = 8,388,608   (bf16)
// [10,567,744)   cn     : C*D*2 = 1,048,576   (bf16)

// Kernel 1: flat streaming scan of labels -> cls[row], cnt histogram.
// Pure HBM-bound: 134MB coalesced float4 reads, ~1 hit per row.
__global__ __launch_bounds__(256) void k_findcls(const float* __restrict__ labels,
                                                 int* __restrict__ cls,
                                                 int* __restrict__ cnt) {
  constexpr size_t total = (size_t)BB * CC / 4;
  size_t q = (size_t)blockIdx.x * blockDim.x + threadIdx.x;
  size_t stride = (size_t)gridDim.x * blockDim.x;
  const float4* l4 = reinterpret_cast<const float4*>(labels);
  for (; q < total; q += stride) {
    float4 v = l4[q];
    if (v.x >= THR || v.y >= THR || v.z >= THR || v.w >= THR) {
      int f = (int)(q * 4);
      int row = f >> 11;      // / CC
      int col = f & (CC - 1);
      int c = col + (v.x >= THR ? 0 : v.y >= THR ? 1 : v.z >= THR ? 2 : 3);
      cls[row] = c;
      atomicAdd(&cnt[c], 1);
    }
  }
}

// Kernel 2: fused pn = normalize(preds) (bf16) + centroid sum atomics.
// One block per row; thread t owns dim t.
__global__ __launch_bounds__(256) void k_prep(const float* __restrict__ preds,
                                              const int* __restrict__ cls,
                                              float* __restrict__ csum,
                                              unsigned short* __restrict__ pn) {
  int b = blockIdx.x;
  int t = threadIdx.x;
  float v = preds[(size_t)b * DD + t];
  float s = v * v;
#pragma unroll
  for (int o = 32; o > 0; o >>= 1) s += __shfl_xor(s, o);
  __shared__ float red[4];
  int wave = t >> 6, lane = t & 63;
  if (lane == 0) red[wave] = s;
  __syncthreads();
  float tot = red[0] + red[1] + red[2] + red[3];
  float inv = 1.0f / fmaxf(sqrtf(tot), EPSN);
  __bf16 h = (__bf16)(v * inv);
  pn[(size_t)b * DD + t] = *reinterpret_cast<unsigned short*>(&h);
  int cl = cls[b];
  if (cl >= 0) atomicAdd(&csum[cl * DD + t], v);
}

// Kernel 3: finalize centroids -> normalized cn (bf16), exists flags, E count.
__global__ __launch_bounds__(256) void k_cn(
    const float* __restrict__ csum, const int* __restrict__ cnt,
    unsigned short* __restrict__ cn, int* __restrict__ exists,
    int* __restrict__ Ecnt) {
  int c = blockIdx.x;
  int t = threadIdx.x;
  int n = cnt[c];
  float mean = csum[c * DD + t] / (float)(n > 0 ? n : 1);
  float s = mean * mean;
#pragma unroll
  for (int o = 32; o > 0; o >>= 1) s += __shfl_xor(s, o);
  __shared__ float red[4];
  int wave = t >> 6, lane = t & 63;
  if (lane == 0) red[wave] = s;
  __syncthreads();
  float tot = red[0] + red[1] + red[2] + red[3];
  float inv = 1.0f / fmaxf(sqrtf(tot), EPSN);
  __bf16 h = (__bf16)(mean * inv);
  cn[c * DD + t] = *reinterpret_cast<unsigned short*>(&h);
  if (t == 0) {
    exists[c] = (n > 0) ? 1 : 0;
    if (n > 0) atomicAdd(Ecnt, 1);
  }
}

// ---- k_loss: LDS-staged MFMA GEMM (m97 structure, 2-phase) + fused epilogue.
// Tile 128x128, BK=64, 4 waves (wave = 32 rows x 128 cols).
// LDS: double-buffered A,B tiles: 4 x 16KB = 64KB -> 2 blocks/CU.
// Swizzle (rule #21, both-sides): element (row, cb in [0,128)) lives at LDS byte
//   row*128 + (cb ^ ((row&7)<<4)); global_load_lds writes linearly, so the
//   SOURCE address is inverse-permuted; ds_read applies the same XOR.
// Reader banks: 16 lanes same cb, rows 0..15 -> 8 distinct 16B slots -> 2-way (free).

__device__ __forceinline__ void stage16(char* lds, const char* gsrc_row0, int tid) {
#pragma unroll
  for (int i = 0; i < 4; ++i) {
    int L = i * 4096 + tid * 16;          // linear LDS byte this thread fills
    int row = L >> 7;                     // 128B per row
    int cb  = (L & 127) ^ ((row & 7) << 4);  // involution: which col-bytes belong here
    const char* g = gsrc_row0 + (size_t)row * (DD * 2) + cb;
    __builtin_amdgcn_global_load_lds(
        (const __attribute__((address_space(1))) unsigned int*)g,
        (__attribute__((address_space(3))) unsigned int*)(lds + L), 16, 0, 0);
  }
}

__device__ __forceinline__ bf16x8 ldfrag(const char* buf, int row, int cb) {
  return *reinterpret_cast<const bf16x8*>(buf + row * 128 + (cb ^ ((row & 7) << 4)));
}

__global__ __launch_bounds__(256) void k_loss(
    const unsigned short* __restrict__ pn, const unsigned short* __restrict__ cn,
    const int* __restrict__ cls, const int* __restrict__ exists,
    const int* __restrict__ Ecnt, float* __restrict__ out) {
  constexpr int BM = 128, BN = 128;
  __shared__ __align__(16) char sA[2][BM * 64 * 2];   // 16KB each
  __shared__ __align__(16) char sB[2][BN * 64 * 2];

  int bid = blockIdx.x;
  int mtile = bid % (BB / BM);
  int ntile = bid / (BB / BM);
  int rowbase = mtile * BM, colbase = ntile * BN;
  int tid = threadIdx.x, w = tid >> 6, lane = tid & 63;
  int r16 = lane & 15, khi = lane >> 4;   // khi in 0..3
  int wr0 = w * 32 + r16;                 // within-tile A row (first of pair)

  const char* pnB = (const char*)pn + (size_t)rowbase * (DD * 2);
  const char* cnB = (const char*)cn + (size_t)colbase * (DD * 2);

  f32x4 acc[2][8];
#pragma unroll
  for (int i = 0; i < 2; ++i)
#pragma unroll
    for (int j = 0; j < 8; ++j) acc[i][j] = {0.f, 0.f, 0.f, 0.f};

  // prologue: stage K-step 0
  stage16(sA[0], pnB, tid);
  stage16(sB[0], cnB, tid);
  __syncthreads();

  int cur = 0;
#pragma unroll
  for (int ks = 0; ks < 4; ++ks) {        // 256 / BK = 4 K-steps
    if (ks < 3) {                          // issue next-tile loads (overlap)
      stage16(sA[cur ^ 1], pnB + (ks + 1) * 128, tid);
      stage16(sB[cur ^ 1], cnB + (ks + 1) * 128, tid);
    }
    const char* bufA = sA[cur];
    const char* bufB = sB[cur];
#pragma unroll
    for (int kk = 0; kk < 2; ++kk) {       // 2 x K=32 MFMA steps per BK=64
      int cb = khi * 16 + kk * 64;
      bf16x8 a0 = ldfrag(bufA, wr0, cb);
      bf16x8 a1 = ldfrag(bufA, wr0 + 16, cb);
#pragma unroll
      for (int j = 0; j < 8; ++j) {
        bf16x8 bj = ldfrag(bufB, j * 16 + r16, cb);
        acc[0][j] = __builtin_amdgcn_mfma_f32_16x16x32_bf16(a0, bj, acc[0][j], 0, 0, 0);
        acc[1][j] = __builtin_amdgcn_mfma_f32_16x16x32_bf16(a1, bj, acc[1][j], 0, 0, 0);
      }
    }
    __syncthreads();                       // drains stage vmcnt + lds reads
    cur ^= 1;
  }

  // Epilogue (verified round 1): pos (diagonal) + hinge neg -> scalar atomic.
  // D layout: col = lane&15, row = (lane>>4)*4 + reg  (m89-verified)
  int E = *Ecnt;
  float inv_B = 1.0f / (float)BB;
  float inv_neg = inv_B / (float)((E - 1) > 0 ? (E - 1) : 1);
  int grow0 = rowbase + w * 32;

  int clsr[2][4];
#pragma unroll
  for (int i = 0; i < 2; ++i)
#pragma unroll
    for (int r = 0; r < 4; ++r) clsr[i][r] = cls[grow0 + i * 16 + khi * 4 + r];
  int exs[8];
#pragma unroll
  for (int j = 0; j < 8; ++j) exs[j] = exists[colbase + j * 16 + r16];

  float local = 0.f;
#pragma unroll
  for (int i = 0; i < 2; ++i)
#pragma unroll
    for (int j = 0; j < 8; ++j) {
      int ccol = colbase + j * 16 + r16;
#pragma unroll
      for (int r = 0; r < 4; ++r) {
        float v = acc[i][j][r];
        if (ccol == clsr[i][r])
          local += (1.0f - v) * inv_B;              // pos: 1 - cos(b, cls[b])
        else if (exs[j])
          local += fmaxf(v - 0.7f, 0.f) * inv_neg;  // relu(M_NEG - (1 - cos))
      }
    }

#pragma unroll
  for (int o = 32; o > 0; o >>= 1) local += __shfl_xor(local, o);
  __shared__ float red[4];
  if (lane == 0) red[w] = local;
  __syncthreads();
  if (tid == 0) atomicAdd(out, red[0] + red[1] + red[2] + red[3]);
}

extern "C" void kernel_launch(void* const* d_in, const int* in_sizes, int n_in,
                              void* d_out, int out_size, void* d_ws, size_t ws_size,
                              hipStream_t stream) {
  const float* preds  = (const float*)d_in[0];
  const float* labels = (const float*)d_in[1];
  float* out = (float*)d_out;

  char* ws = (char*)d_ws;
  float*          csum   = (float*)(ws + 0);
  int*            cnt    = (int*)(ws + 2097152);
  int*            Ecnt   = (int*)(ws + 2105344);
  int*            cls    = (int*)(ws + 2105408);
  int*            exists = (int*)(ws + 2170944);
  unsigned short* pn     = (unsigned short*)(ws + 2179136);
  unsigned short* cn     = (unsigned short*)(ws + 10567744);

  hipMemsetAsync(ws, 0, 2105408, stream);              // csum + cnt + Ecnt
  hipMemsetAsync(d_out, 0, sizeof(float), stream);

  k_findcls<<<2048, 256, 0, stream>>>(labels, cls, cnt);
  k_prep<<<BB, 256, 0, stream>>>(preds, cls, csum, pn);
  k_cn<<<CC, 256, 0, stream>>>(csum, cnt, cn, exists, Ecnt);
  k_loss<<<(BB / 128) * (CC / 128), 256, 0, stream>>>(pn, cn, cls, exists, Ecnt, out);
}

// Round 3
// 109.304 us; speedup vs baseline: 1.5299x; 1.0826x over previous
//
#include <hip/hip_runtime.h>
#include <hip/hip_bf16.h>

// Problem constants (match reference)
constexpr int BB = 16384;   // batch
constexpr int CC = 2048;    // classes
constexpr int DD = 256;     // dim
constexpr float THR   = 0.8f;
constexpr float EPSN  = 1e-8f;

typedef __bf16 bf16x8 __attribute__((ext_vector_type(8)));
typedef float  f32x4  __attribute__((ext_vector_type(4)));

// ---------------- workspace layout (bytes) ----------------
// [0)         cnt     : C*4   = 8,192      (zeroed each launch)
// [8,192)     Ecnt    : 4 (pad to 8,256)   (zeroed)
// [8,256)     cls     : B*4   = 65,536
// [73,792)    rowlist : C*64*4 = 524,288   (slot-guarded, no zero needed)
// [598,080)   exists  : C*4   = 8,192
// [606,272)   pn      : B*D*2 = 8,388,608  (bf16)
// [8,994,880) cn      : C*D*2 = 1,048,576  (bf16)
constexpr int ROWSLOTS = 64;  // Poisson(8) max over 2048 classes << 64

// Kernel 1: flat streaming scan of labels -> cls[row], cnt histogram, rowlist.
// Pure HBM-bound: 134MB coalesced float4 reads; ~1 atomic per ROW (16K total).
__global__ __launch_bounds__(256) void k_findcls(const float* __restrict__ labels,
                                                 int* __restrict__ cls,
                                                 int* __restrict__ cnt,
                                                 int* __restrict__ rowlist) {
  constexpr size_t total = (size_t)BB * CC / 4;
  size_t q = (size_t)blockIdx.x * blockDim.x + threadIdx.x;
  size_t stride = (size_t)gridDim.x * blockDim.x;
  const float4* l4 = reinterpret_cast<const float4*>(labels);
  for (; q < total; q += stride) {
    float4 v = l4[q];
    if (v.x >= THR || v.y >= THR || v.z >= THR || v.w >= THR) {
      int f = (int)(q * 4);
      int row = f >> 11;      // / CC
      int col = f & (CC - 1);
      int c = col + (v.x >= THR ? 0 : v.y >= THR ? 1 : v.z >= THR ? 2 : 3);
      cls[row] = c;
      int s = atomicAdd(&cnt[c], 1);
      if (s < ROWSLOTS) rowlist[c * ROWSLOTS + s] = row;
    }
  }
}

// Kernel 2: pn = normalize(preds) stored bf16. One WAVE per row, no LDS.
__global__ __launch_bounds__(256) void k_pn(const float* __restrict__ preds,
                                            unsigned short* __restrict__ pn) {
  int b = blockIdx.x * 4 + (threadIdx.x >> 6);
  int lane = threadIdx.x & 63;
  float4 v = reinterpret_cast<const float4*>(preds + (size_t)b * DD)[lane];
  float s = v.x * v.x + v.y * v.y + v.z * v.z + v.w * v.w;
#pragma unroll
  for (int o = 32; o > 0; o >>= 1) s += __shfl_xor(s, o);
  float inv = 1.0f / fmaxf(sqrtf(s), EPSN);
  union { ushort4 u4; unsigned short us[4]; } o;
  float f0 = v.x * inv, f1 = v.y * inv, f2 = v.z * inv, f3 = v.w * inv;
  __bf16 h0 = (__bf16)f0, h1 = (__bf16)f1, h2 = (__bf16)f2, h3 = (__bf16)f3;
  o.us[0] = *reinterpret_cast<unsigned short*>(&h0);
  o.us[1] = *reinterpret_cast<unsigned short*>(&h1);
  o.us[2] = *reinterpret_cast<unsigned short*>(&h2);
  o.us[3] = *reinterpret_cast<unsigned short*>(&h3);
  reinterpret_cast<ushort4*>(pn + (size_t)b * DD)[lane] = o.u4;
}

// Kernel 3: block per class: gather its ~8 rows via rowlist, mean, normalize,
// write cn (bf16) + exists + Ecnt. No csum atomics at all.
__global__ __launch_bounds__(256) void k_cn(
    const float* __restrict__ preds, const int* __restrict__ cnt,
    const int* __restrict__ rowlist, unsigned short* __restrict__ cn,
    int* __restrict__ exists, int* __restrict__ Ecnt) {
  int c = blockIdx.x;
  int t = threadIdx.x;
  int n = cnt[c];
  int nn = n < ROWSLOTS ? n : ROWSLOTS;
  float sum = 0.f;
  for (int i = 0; i < nn; ++i) {
    int row = rowlist[c * ROWSLOTS + i];
    sum += preds[(size_t)row * DD + t];
  }
  float mean = sum / (float)(n > 0 ? n : 1);
  float s = mean * mean;
#pragma unroll
  for (int o = 32; o > 0; o >>= 1) s += __shfl_xor(s, o);
  __shared__ float red[4];
  int wave = t >> 6, lane = t & 63;
  if (lane == 0) red[wave] = s;
  __syncthreads();
  float tot = red[0] + red[1] + red[2] + red[3];
  float inv = 1.0f / fmaxf(sqrtf(tot), EPSN);
  __bf16 h = (__bf16)(mean * inv);
  cn[c * DD + t] = *reinterpret_cast<unsigned short*>(&h);
  if (t == 0) {
    exists[c] = (n > 0) ? 1 : 0;
    if (n > 0) atomicAdd(Ecnt, 1);
  }
}

// ---- k_loss: LDS-staged MFMA GEMM (m97 single-buffer 2-barrier structure).
// Tile 128x128, BK=64, 4 waves; LDS 32KB -> 5 blocks/CU (inter-block overlap
// hides the stage stall per m97/m114). T1 XCD swizzle for cn-panel L2 reuse.
// Swizzle (rule #21, both-sides): element (row, cb) at byte row*128 + (cb ^
// ((row&7)<<4)); global_load_lds writes linearly -> SOURCE inverse-permuted,
// ds_read applies the same XOR. Verified round 2 (bank conflicts = 0).

__device__ __forceinline__ void stage16(char* lds, const char* gsrc_row0, int tid) {
#pragma unroll
  for (int i = 0; i < 4; ++i) {
    int L = i * 4096 + tid * 16;             // linear LDS byte this thread fills
    int row = L >> 7;                        // 128B per row
    int cb  = (L & 127) ^ ((row & 7) << 4);  // involution
    const char* g = gsrc_row0 + (size_t)row * (DD * 2) + cb;
    __builtin_amdgcn_global_load_lds(
        (const __attribute__((address_space(1))) unsigned int*)g,
        (__attribute__((address_space(3))) unsigned int*)(lds + L), 16, 0, 0);
  }
}

__device__ __forceinline__ bf16x8 ldfrag(const char* buf, int row, int cb) {
  return *reinterpret_cast<const bf16x8*>(buf + row * 128 + (cb ^ ((row & 7) << 4)));
}

__global__ __launch_bounds__(256) void k_loss(
    const unsigned short* __restrict__ pn, const unsigned short* __restrict__ cn,
    const int* __restrict__ cls, const int* __restrict__ exists,
    const int* __restrict__ Ecnt, float* __restrict__ out) {
  constexpr int BM = 128, BN = 128;
  __shared__ __align__(16) char sA[BM * 64 * 2];   // 16KB
  __shared__ __align__(16) char sB[BN * 64 * 2];   // 16KB

  // T1 XCD swizzle: 2048 blocks, 2048 % 8 == 0 -> bijective chunked remap.
  int bid = blockIdx.x;
  int nb = (bid & 7) * (2048 / 8) + (bid >> 3);
  int mtile = nb % (BB / BM);
  int ntile = nb / (BB / BM);
  int rowbase = mtile * BM, colbase = ntile * BN;
  int tid = threadIdx.x, w = tid >> 6, lane = tid & 63;
  int r16 = lane & 15, khi = lane >> 4;   // khi in 0..3
  int wr0 = w * 32 + r16;                 // within-tile A row (first of pair)

  const char* pnB = (const char*)pn + (size_t)rowbase * (DD * 2);
  const char* cnB = (const char*)cn + (size_t)colbase * (DD * 2);

  f32x4 acc[2][8];
#pragma unroll
  for (int i = 0; i < 2; ++i)
#pragma unroll
    for (int j = 0; j < 8; ++j) acc[i][j] = {0.f, 0.f, 0.f, 0.f};

#pragma unroll
  for (int ks = 0; ks < 4; ++ks) {        // 256 / BK = 4 K-steps
    stage16(sA, pnB + ks * 128, tid);
    stage16(sB, cnB + ks * 128, tid);
    __syncthreads();                      // stage complete (vmcnt drained)
#pragma unroll
    for (int kk = 0; kk < 2; ++kk) {      // 2 x K=32 MFMA steps per BK=64
      int cb = khi * 16 + kk * 64;
      bf16x8 a0 = ldfrag(sA, wr0, cb);
      bf16x8 a1 = ldfrag(sA, wr0 + 16, cb);
#pragma unroll
      for (int j = 0; j < 8; ++j) {
        bf16x8 bj = ldfrag(sB, j * 16 + r16, cb);
        acc[0][j] = __builtin_amdgcn_mfma_f32_16x16x32_bf16(a0, bj, acc[0][j], 0, 0, 0);
        acc[1][j] = __builtin_amdgcn_mfma_f32_16x16x32_bf16(a1, bj, acc[1][j], 0, 0, 0);
      }
    }
    if (ks < 3) __syncthreads();          // reads done before next overwrite
  }

  // Epilogue (verified rounds 1-2): pos (diagonal) + hinge neg -> scalar atomic.
  // D layout: col = lane&15, row = (lane>>4)*4 + reg  (m89-verified)
  int E = *Ecnt;
  float inv_B = 1.0f / (float)BB;
  float inv_neg = inv_B / (float)((E - 1) > 0 ? (E - 1) : 1);
  int grow0 = rowbase + w * 32;

  int clsr[2][4];
#pragma unroll
  for (int i = 0; i < 2; ++i)
#pragma unroll
    for (int r = 0; r < 4; ++r) clsr[i][r] = cls[grow0 + i * 16 + khi * 4 + r];
  int exs[8];
#pragma unroll
  for (int j = 0; j < 8; ++j) exs[j] = exists[colbase + j * 16 + r16];

  float local = 0.f;
#pragma unroll
  for (int i = 0; i < 2; ++i)
#pragma unroll
    for (int j = 0; j < 8; ++j) {
      int ccol = colbase + j * 16 + r16;
#pragma unroll
      for (int r = 0; r < 4; ++r) {
        float v = acc[i][j][r];
        if (ccol == clsr[i][r])
          local += (1.0f - v) * inv_B;              // pos: 1 - cos(b, cls[b])
        else if (exs[j])
          local += fmaxf(v - 0.7f, 0.f) * inv_neg;  // relu(M_NEG - (1 - cos))
      }
    }

#pragma unroll
  for (int o = 32; o > 0; o >>= 1) local += __shfl_xor(local, o);
  __shared__ float red[4];
  if (lane == 0) red[w] = local;
  __syncthreads();
  if (tid == 0) atomicAdd(out, red[0] + red[1] + red[2] + red[3]);
}

extern "C" void kernel_launch(void* const* d_in, const int* in_sizes, int n_in,
                              void* d_out, int out_size, void* d_ws, size_t ws_size,
                              hipStream_t stream) {
  const float* preds  = (const float*)d_in[0];
  const float* labels = (const float*)d_in[1];
  float* out = (float*)d_out;

  char* ws = (char*)d_ws;
  int*            cnt     = (int*)(ws + 0);
  int*            Ecnt    = (int*)(ws + 8192);
  int*            cls     = (int*)(ws + 8256);
  int*            rowlist = (int*)(ws + 73792);
  int*            exists  = (int*)(ws + 598080);
  unsigned short* pn      = (unsigned short*)(ws + 606272);
  unsigned short* cn      = (unsigned short*)(ws + 8994880);

  hipMemsetAsync(ws, 0, 8256, stream);                 // cnt + Ecnt
  hipMemsetAsync(d_out, 0, sizeof(float), stream);

  k_findcls<<<2048, 256, 0, stream>>>(labels, cls, cnt, rowlist);
  k_pn<<<BB / 4, 256, 0, stream>>>(preds, pn);
  k_cn<<<CC, 256, 0, stream>>>(preds, cnt, rowlist, cn, exists, Ecnt);
  k_loss<<<(BB / 128) * (CC / 128), 256, 0, stream>>>(pn, cn, cls, exists, Ecnt, out);
}

// Round 4
// 96.570 us; speedup vs baseline: 1.7316x; 1.1319x over previous
//
#include <hip/hip_runtime.h>
#include <hip/hip_bf16.h>

// Problem constants (match reference)
constexpr int BB = 16384;   // batch
constexpr int CC = 2048;    // classes
constexpr int DD = 256;     // dim
constexpr float THR   = 0.8f;
constexpr float EPSN  = 1e-8f;

typedef __bf16 bf16x8 __attribute__((ext_vector_type(8)));
typedef float  f32x4  __attribute__((ext_vector_type(4)));

// ---------------- workspace layout (bytes) ----------------
// [0)         cnt     : C*4   = 8,192      (zeroed each launch)
// [8,192)     Ecnt    : 4 (pad to 8,256)   (zeroed)
// [8,256)     cls     : B*4   = 65,536
// [73,792)    rowlist : C*64*4 = 524,288   (slot-guarded, no zero needed)
// [598,080)   exists  : C*4   = 8,192
// [606,272)   pn      : B*D*2 = 8,388,608  (bf16)
// [8,994,880) cn      : C*D*2 = 1,048,576  (bf16)
constexpr int ROWSLOTS = 64;  // Poisson(8) max over 2048 classes << 64

// Fat kernel: blocks [0,2048) stream labels -> cls/cnt/rowlist (+ out=0);
//             blocks [2048,6144) normalize preds -> pn (bf16), 1 wave/row.
__global__ __launch_bounds__(256) void k_prep(const float* __restrict__ labels,
                                              const float* __restrict__ preds,
                                              int* __restrict__ cls,
                                              int* __restrict__ cnt,
                                              int* __restrict__ rowlist,
                                              unsigned short* __restrict__ pn,
                                              float* __restrict__ out) {
  if (blockIdx.x < 2048) {
    if (blockIdx.x == 0 && threadIdx.x == 0) *out = 0.f;
    constexpr size_t total = (size_t)BB * CC / 4;
    size_t q = (size_t)blockIdx.x * 256 + threadIdx.x;
    const float4* l4 = reinterpret_cast<const float4*>(labels);
    for (; q < total; q += 2048 * 256) {
      float4 v = l4[q];
      if (v.x >= THR || v.y >= THR || v.z >= THR || v.w >= THR) {
        int f = (int)(q * 4);
        int row = f >> 11;      // / CC
        int col = f & (CC - 1);
        int c = col + (v.x >= THR ? 0 : v.y >= THR ? 1 : v.z >= THR ? 2 : 3);
        cls[row] = c;
        int s = atomicAdd(&cnt[c], 1);
        if (s < ROWSLOTS) rowlist[c * ROWSLOTS + s] = row;
      }
    }
  } else {
    int b = (blockIdx.x - 2048) * 4 + (threadIdx.x >> 6);
    int lane = threadIdx.x & 63;
    float4 v = reinterpret_cast<const float4*>(preds + (size_t)b * DD)[lane];
    float s = v.x * v.x + v.y * v.y + v.z * v.z + v.w * v.w;
#pragma unroll
    for (int o = 32; o > 0; o >>= 1) s += __shfl_xor(s, o);
    float inv = 1.0f / fmaxf(sqrtf(s), EPSN);
    union { ushort4 u4; unsigned short us[4]; } o;
    float f0 = v.x * inv, f1 = v.y * inv, f2 = v.z * inv, f3 = v.w * inv;
    __bf16 h0 = (__bf16)f0, h1 = (__bf16)f1, h2 = (__bf16)f2, h3 = (__bf16)f3;
    o.us[0] = *reinterpret_cast<unsigned short*>(&h0);
    o.us[1] = *reinterpret_cast<unsigned short*>(&h1);
    o.us[2] = *reinterpret_cast<unsigned short*>(&h2);
    o.us[3] = *reinterpret_cast<unsigned short*>(&h3);
    reinterpret_cast<ushort4*>(pn + (size_t)b * DD)[lane] = o.u4;
  }
}

// Per-class: gather ~8 rows via rowlist, mean, normalize -> cn bf16 + exists/Ecnt.
__global__ __launch_bounds__(256) void k_cn(
    const float* __restrict__ preds, const int* __restrict__ cnt,
    const int* __restrict__ rowlist, unsigned short* __restrict__ cn,
    int* __restrict__ exists, int* __restrict__ Ecnt) {
  int c = blockIdx.x;
  int t = threadIdx.x;
  int n = cnt[c];
  int nn = n < ROWSLOTS ? n : ROWSLOTS;
  float sum = 0.f;
  for (int i = 0; i < nn; ++i) {
    int row = rowlist[c * ROWSLOTS + i];
    sum += preds[(size_t)row * DD + t];
  }
  float mean = sum / (float)(n > 0 ? n : 1);
  float s = mean * mean;
#pragma unroll
  for (int o = 32; o > 0; o >>= 1) s += __shfl_xor(s, o);
  __shared__ float red[4];
  int wave = t >> 6, lane = t & 63;
  if (lane == 0) red[wave] = s;
  __syncthreads();
  float tot = red[0] + red[1] + red[2] + red[3];
  float inv = 1.0f / fmaxf(sqrtf(tot), EPSN);
  __bf16 h = (__bf16)(mean * inv);
  cn[c * DD + t] = *reinterpret_cast<unsigned short*>(&h);
  if (t == 0) {
    exists[c] = (n > 0) ? 1 : 0;
    if (n > 0) atomicAdd(Ecnt, 1);
  }
}

// ---- k_loss: 256x256 tile, BK=64, 8 waves (512 thr), dbuf 128KB LDS, 2-phase.
// Wave = 128 rows x 64 cols: acc[8][4] 16x16 frags. Per K-step per wave:
// 2 kk x (8 a + 4 b ds_read_b128 + 32 MFMA) -> ~2500cy MFMA per step hides the
// ~500cy stage latency (stage issued BEFORE compute, single barrier per step).
// Swizzle (rule #21, both-sides, verified r2/r3 conflict-free): element
// (row, kb) at byte row*128 + (kb ^ ((row&7)<<4)); global_load_lds dest is
// linear, SOURCE inverse-permuted, ds_read applies the same XOR.
// XCD swizzle: nb = (bid%8)*64 + bid/8 -> each XCD owns one ntile (cn panel
// stays in its L2; pn streamed once per XCD from L3).

__device__ __forceinline__ void stage32k(char* lds, const char* gsrc_row0,
                                         int tid, int ksbyte) {
#pragma unroll
  for (int i = 0; i < 4; ++i) {
    int L = i * 8192 + tid * 16;             // linear LDS byte (32KB / 512thr)
    int row = L >> 7;                        // 128B per row (64 k * 2B)
    int kb  = (L & 127) ^ ((row & 7) << 4);  // involution
    const char* g = gsrc_row0 + (size_t)row * (DD * 2) + ksbyte + kb;
    __builtin_amdgcn_global_load_lds(
        (const __attribute__((address_space(1))) unsigned int*)g,
        (__attribute__((address_space(3))) unsigned int*)(lds + L), 16, 0, 0);
  }
}

__device__ __forceinline__ bf16x8 ldfrag(const char* buf, int row, int kb) {
  return *reinterpret_cast<const bf16x8*>(buf + row * 128 + (kb ^ ((row & 7) << 4)));
}

__global__ __launch_bounds__(512, 2) void k_loss(
    const unsigned short* __restrict__ pn, const unsigned short* __restrict__ cn,
    const int* __restrict__ cls, const int* __restrict__ exists,
    const int* __restrict__ Ecnt, float* __restrict__ out) {
  constexpr int BM = 256, BN = 256;
  __shared__ __align__(16) char sA[2][BM * 64 * 2];   // 2 x 32KB
  __shared__ __align__(16) char sB[2][BN * 64 * 2];   // 2 x 32KB
  __shared__ float red[8];

  // 512 blocks = 64 mtiles x 8 ntiles; bijective XCD swizzle (512 % 8 == 0).
  int bid = blockIdx.x;
  int nb = (bid & 7) * 64 + (bid >> 3);
  int mtile = nb & 63;
  int ntile = nb >> 6;
  int rowbase = mtile * BM, colbase = ntile * BN;
  int tid = threadIdx.x, w = tid >> 6, lane = tid & 63;
  int wm = w >> 2, wn = w & 3;            // wave grid 2 x 4
  int r16 = lane & 15, khi = lane >> 4;   // khi in 0..3
  int arow0 = wm * 128 + r16;             // LDS-A row base for a-frags
  int brow0 = wn * 64 + r16;              // LDS-B row base for b-frags

  const char* pnB = (const char*)pn + (size_t)rowbase * (DD * 2);
  const char* cnB = (const char*)cn + (size_t)colbase * (DD * 2);

  f32x4 acc[8][4];
#pragma unroll
  for (int m = 0; m < 8; ++m)
#pragma unroll
    for (int n = 0; n < 4; ++n) acc[m][n] = {0.f, 0.f, 0.f, 0.f};

  stage32k(sA[0], pnB, tid, 0);
  stage32k(sB[0], cnB, tid, 0);
  __syncthreads();

  int cur = 0;
#pragma unroll
  for (int ks = 0; ks < 4; ++ks) {        // 256 / BK = 4 K-steps
    if (ks < 3) {                         // issue next stage BEFORE compute
      stage32k(sA[cur ^ 1], pnB, tid, (ks + 1) * 128);
      stage32k(sB[cur ^ 1], cnB, tid, (ks + 1) * 128);
    }
    const char* bufA = sA[cur];
    const char* bufB = sB[cur];
#pragma unroll
    for (int kk = 0; kk < 2; ++kk) {      // 2 x K=32 per BK=64
      int kb = kk * 64 + khi * 16;
      bf16x8 b[4];
#pragma unroll
      for (int n = 0; n < 4; ++n) b[n] = ldfrag(bufB, brow0 + n * 16, kb);
#pragma unroll
      for (int m = 0; m < 8; ++m) {
        bf16x8 a = ldfrag(bufA, arow0 + m * 16, kb);
#pragma unroll
        for (int n = 0; n < 4; ++n)
          acc[m][n] = __builtin_amdgcn_mfma_f32_16x16x32_bf16(a, b[n], acc[m][n], 0, 0, 0);
      }
    }
    __syncthreads();                      // drains next-stage vmcnt + lds reads
    cur ^= 1;
  }

  // Epilogue: pos (diagonal) + hinge neg -> scalar atomic.
  // D layout: col = lane&15, row = (lane>>4)*4 + reg  (m89-verified)
  int E = *Ecnt;
  float inv_B = 1.0f / (float)BB;
  float inv_neg = inv_B / (float)((E - 1) > 0 ? (E - 1) : 1);
  int grow0 = rowbase + wm * 128;

  int clsr[8][4];
#pragma unroll
  for (int m = 0; m < 8; ++m)
#pragma unroll
    for (int r = 0; r < 4; ++r) clsr[m][r] = cls[grow0 + m * 16 + khi * 4 + r];
  int exs[4];
#pragma unroll
  for (int n = 0; n < 4; ++n) exs[n] = exists[colbase + wn * 64 + n * 16 + r16];

  float local = 0.f;
#pragma unroll
  for (int m = 0; m < 8; ++m)
#pragma unroll
    for (int n = 0; n < 4; ++n) {
      int ccol = colbase + wn * 64 + n * 16 + r16;
#pragma unroll
      for (int r = 0; r < 4; ++r) {
        float v = acc[m][n][r];
        if (ccol == clsr[m][r])
          local += (1.0f - v) * inv_B;              // pos: 1 - cos(b, cls[b])
        else if (exs[n])
          local += fmaxf(v - 0.7f, 0.f) * inv_neg;  // relu(M_NEG - (1 - cos))
      }
    }

#pragma unroll
  for (int o = 32; o > 0; o >>= 1) local += __shfl_xor(local, o);
  if (lane == 0) red[w] = local;
  __syncthreads();
  if (tid == 0) {
    float t = 0.f;
#pragma unroll
    for (int i = 0; i < 8; ++i) t += red[i];
    atomicAdd(out, t);
  }
}

extern "C" void kernel_launch(void* const* d_in, const int* in_sizes, int n_in,
                              void* d_out, int out_size, void* d_ws, size_t ws_size,
                              hipStream_t stream) {
  const float* preds  = (const float*)d_in[0];
  const float* labels = (const float*)d_in[1];
  float* out = (float*)d_out;

  char* ws = (char*)d_ws;
  int*            cnt     = (int*)(ws + 0);
  int*            Ecnt    = (int*)(ws + 8192);
  int*            cls     = (int*)(ws + 8256);
  int*            rowlist = (int*)(ws + 73792);
  int*            exists  = (int*)(ws + 598080);
  unsigned short* pn      = (unsigned short*)(ws + 606272);
  unsigned short* cn      = (unsigned short*)(ws + 8994880);

  hipMemsetAsync(ws, 0, 8256, stream);                 // cnt + Ecnt
  k_prep<<<6144, 256, 0, stream>>>(labels, preds, cls, cnt, rowlist, pn, out);
  k_cn<<<CC, 256, 0, stream>>>(preds, cnt, rowlist, cn, exists, Ecnt);
  k_loss<<<512, 512, 0, stream>>>(pn, cn, cls, exists, Ecnt, out);
}